// Round 14
// baseline (476.327 us; speedup 1.0000x reference)
//
#include <hip/hip_runtime.h>
#include <hip/hip_bf16.h>
#include <math.h>

#define NN 4096
#define NE 16384
#define NLAYERS 4

// per-layer short layout of split weights:
// [wq_t 131072 | wk_t 131072 | wv_t 131072 | wsk_t 16384 | wqe_t 32768] = 442368
#define WT_STRIDE 442368

typedef __attribute__((ext_vector_type(8))) short bf16x8;
typedef __attribute__((ext_vector_type(4))) float floatx4;

__device__ __forceinline__ float gelu_f(float x) {
  return 0.5f * x * (1.0f + erff(x * 0.70710678118654752440f));
}

// split f32 into hi+lo bf16 (hi = RN(a), lo = RN(a - hi)); hi+lo accurate to ~2^-17
__device__ __forceinline__ void bsplit(float a, unsigned short& hi, unsigned short& lo) {
  __hip_bfloat16 h16 = __float2bfloat16(a);
  hi = *(unsigned short*)&h16;
  const float r = a - __bfloat162float(h16);
  __hip_bfloat16 l16 = __float2bfloat16(r);
  lo = *(unsigned short*)&l16;
}

union F16U { float4 v4[4]; float f[16]; };

__global__ void k_init(const int* __restrict__ x, const float* __restrict__ atom_emb,
                       const float* __restrict__ edge_attr, const float* __restrict__ edge_w,
                       const float* __restrict__ edge_b, float* __restrict__ h,
                       float* __restrict__ ef, int* __restrict__ counts,
                       unsigned short* __restrict__ hhi, unsigned short* __restrict__ hlo) {
  const int idx = blockIdx.x * 256 + threadIdx.x;      // 0..524287 (= NN*128 = NE*32)
  const float hv = atom_emb[x[idx >> 7] * 128 + (idx & 127)];
  h[idx] = hv;
  bsplit(hv, hhi[idx], hlo[idx]);
  ef[idx] = edge_attr[idx >> 5] * edge_w[idx & 31] + edge_b[idx & 31];
  if (idx < NN) counts[idx] = 0;
}

__global__ void k_hist(const int* __restrict__ eidx, int* __restrict__ counts) {
  const int e = blockIdx.x * 256 + threadIdx.x;
  if (e < NE) atomicAdd(&counts[eidx[NE + e]], 1);
}

// scan + scatter fused: prefix-sum counts -> offs; bucket edges via LDS atomics.
__global__ void k_scan2(const int* __restrict__ counts, int* __restrict__ offs,
                        const int* __restrict__ eidx, int* __restrict__ elist) {
  __shared__ int tmp[1024];
  __shared__ int sheads[4096];
  const int t = threadIdx.x;
  const int c0 = counts[t*4], c1 = counts[t*4+1], c2 = counts[t*4+2], c3 = counts[t*4+3];
  const int s = c0 + c1 + c2 + c3;
  tmp[t] = s; __syncthreads();
  for (int off = 1; off < 1024; off <<= 1) {
    int v = (t >= off) ? tmp[t - off] : 0;
    __syncthreads();
    tmp[t] += v;
    __syncthreads();
  }
  int base = tmp[t] - s;
  offs[t*4]   = base;                sheads[t*4]   = base;
  offs[t*4+1] = base + c0;           sheads[t*4+1] = base + c0;
  offs[t*4+2] = base + c0 + c1;      sheads[t*4+2] = base + c0 + c1;
  offs[t*4+3] = base + c0 + c1 + c2; sheads[t*4+3] = base + c0 + c1 + c2;
  if (t == 1023) offs[NN] = tmp[1023];
  __syncthreads();
  for (int e = t; e < NE; e += 1024) {
    const int p = atomicAdd(&sheads[eidx[NE + e]], 1);
    elist[p] = e;
  }
}

// one-time: split + transpose all layer weights -> wthi/wtlo[n][k] bf16
__global__ __launch_bounds__(256) void k_wcvt(
    const float* __restrict__ wq, const float* __restrict__ wk,
    const float* __restrict__ wv, const float* __restrict__ wsk,
    unsigned short* __restrict__ wthi, unsigned short* __restrict__ wtlo) {
  const int z = blockIdx.z;            // layer*4 + mat
  const int layer = z >> 2, mat = z & 3;
  int NC; const float* W; int woff;
  if (mat == 0)      { NC = 1024; W = wq  + (size_t)layer * 131072; woff = 0; }
  else if (mat == 1) { NC = 1024; W = wk  + (size_t)layer * 131072; woff = 131072; }
  else if (mat == 2) { NC = 1024; W = wv  + (size_t)layer * 131072; woff = 262144; }
  else               { NC = 128;  W = wsk + (size_t)layer * 16384;  woff = 393216; }
  const int c0 = blockIdx.x * 64;
  if (c0 >= NC) return;
  const int k0 = blockIdx.y * 64;
  __shared__ unsigned short th[64][65], tl[64][65];
  const int t = threadIdx.x;
  for (int i = t; i < 4096; i += 256) {
    const int kk = i >> 6, c = i & 63;
    bsplit(W[(size_t)(k0 + kk) * NC + c0 + c], th[kk][c], tl[kk][c]);
  }
  __syncthreads();
  unsigned short* oh = wthi + (size_t)layer * WT_STRIDE + woff;
  unsigned short* ol = wtlo + (size_t)layer * WT_STRIDE + woff;
  for (int i = t; i < 4096; i += 256) {
    const int n = i >> 6, k = i & 63;
    oh[(size_t)(c0 + n) * 128 + k0 + k] = th[k][n];
    ol[(size_t)(c0 + n) * 128 + k0 + k] = tl[k][n];
  }
}

// one-time: composed qe weight.  qe = h @ Wqe_t^T + bqe where
// Wqe_t[j=hh*32+c][d] = sum_dd wq[d][hh*128+dd] * we[c][hh*128+dd]
// bqe[j]             = sum_dd bq[hh*128+dd]     * we[c][hh*128+dd]
__global__ __launch_bounds__(256) void k_wqe(
    const float* __restrict__ wq, const float* __restrict__ bq,
    const float* __restrict__ we, unsigned short* __restrict__ wthi,
    unsigned short* __restrict__ wtlo, float* __restrict__ bqe) {
  const int layer = blockIdx.x >> 3, hh = blockIdx.x & 7;
  const float* wq_l = wq + (size_t)layer * 131072;   // [128][1024]
  const float* we_l = we + (size_t)layer * 32768;    // [32][1024]
  const float* bq_l = bq + (size_t)layer * 1024;
  __shared__ float wqS[128][132];   // wqS[d][dd]
  __shared__ float weS[32][132];    // weS[c][dd]
  const int t = threadIdx.x;
  for (int i = t; i < 4096; i += 256) {               // 128 rows x 32 float4
    const int d = i >> 5, dd4 = (i & 31) << 2;
    *(float4*)&wqS[d][dd4] = *(const float4*)&wq_l[(size_t)d * 1024 + hh * 128 + dd4];
  }
  for (int i = t; i < 1024; i += 256) {               // 32 rows x 32 float4
    const int c = i >> 5, dd4 = (i & 31) << 2;
    *(float4*)&weS[c][dd4] = *(const float4*)&we_l[(size_t)c * 1024 + hh * 128 + dd4];
  }
  __syncthreads();
  const int d = t & 127, cg = t >> 7;                 // each thread: 16 c values
  float acc[16];
  #pragma unroll
  for (int cc = 0; cc < 16; cc++) acc[cc] = 0.f;
  for (int dd = 0; dd < 128; dd++) {
    const float a = wqS[d][dd];
    #pragma unroll
    for (int cc = 0; cc < 16; cc++)
      acc[cc] += a * weS[cg * 16 + cc][dd];
  }
  unsigned short* oh = wthi + (size_t)layer * WT_STRIDE + 409600;
  unsigned short* ol = wtlo + (size_t)layer * WT_STRIDE + 409600;
  #pragma unroll
  for (int cc = 0; cc < 16; cc++) {
    const int j = hh * 32 + cg * 16 + cc;
    unsigned short hi, lo;
    bsplit(acc[cc], hi, lo);
    oh[(size_t)j * 128 + d] = hi;
    ol[(size_t)j * 128 + d] = lo;
  }
  if (t < 32) {
    float s = 0.f;
    for (int dd = 0; dd < 128; dd++) s += bq_l[hh * 128 + dd] * weS[t][dd];
    bqe[layer * 256 + hh * 32 + t] = s;
  }
}

// fused q/k/v/skip/qe GEMM via split-bf16 MFMA (3 passes: hi*hi + hi*lo + lo*hi).
// single grid: x in [0,54) spans all 5 output matrices' 64-col tiles.
__global__ __launch_bounds__(256) void k_mfqkv(
    const unsigned short* __restrict__ hhi, const unsigned short* __restrict__ hlo,
    const unsigned short* __restrict__ wth, const unsigned short* __restrict__ wtl,
    const float* __restrict__ bq, const float* __restrict__ bk,
    const float* __restrict__ bv, const float* __restrict__ bsk,
    const float* __restrict__ bqe_l,
    float* __restrict__ qb, float* __restrict__ kb,
    float* __restrict__ vb, float* __restrict__ skb, float* __restrict__ qeb) {
  const int xb = blockIdx.x;
  int NC; const float* bias; float* C; int woff; int c0;
  if (xb < 16)      { NC = 1024; bias = bq;    C = qb;  woff = 0;      c0 = xb * 64; }
  else if (xb < 32) { NC = 1024; bias = bk;    C = kb;  woff = 131072; c0 = (xb-16) * 64; }
  else if (xb < 48) { NC = 1024; bias = bv;    C = vb;  woff = 262144; c0 = (xb-32) * 64; }
  else if (xb < 50) { NC = 128;  bias = bsk;   C = skb; woff = 393216; c0 = (xb-48) * 64; }
  else              { NC = 256;  bias = bqe_l; C = qeb; woff = 409600; c0 = (xb-50) * 64; }
  __shared__ unsigned short Ah[64][136], Al[64][136], Wh[64][136], Wl[64][136];
  const int t = threadIdx.x;
  const int n0 = blockIdx.y * 64;
  for (int i = t; i < 1024; i += 256) {
    const int r = i >> 4, c8 = (i & 15) << 3;
    *(uint4*)&Ah[r][c8] = *(const uint4*)&hhi[(size_t)(n0 + r) * 128 + c8];
    *(uint4*)&Al[r][c8] = *(const uint4*)&hlo[(size_t)(n0 + r) * 128 + c8];
    *(uint4*)&Wh[r][c8] = *(const uint4*)&wth[woff + (size_t)(c0 + r) * 128 + c8];
    *(uint4*)&Wl[r][c8] = *(const uint4*)&wtl[woff + (size_t)(c0 + r) * 128 + c8];
  }
  __syncthreads();
  const int w = t >> 6, l = t & 63;
  const int quad = l >> 4, lm = l & 15;
  floatx4 acc[4] = {{0.f,0.f,0.f,0.f},{0.f,0.f,0.f,0.f},{0.f,0.f,0.f,0.f},{0.f,0.f,0.f,0.f}};
  #pragma unroll
  for (int kc = 0; kc < 4; kc++) {
    const int ko = kc * 32 + quad * 8;
    const bf16x8 ah = *(const bf16x8*)&Ah[w * 16 + lm][ko];
    const bf16x8 al = *(const bf16x8*)&Al[w * 16 + lm][ko];
    #pragma unroll
    for (int ct = 0; ct < 4; ct++) {
      const bf16x8 bh = *(const bf16x8*)&Wh[ct * 16 + lm][ko];
      const bf16x8 bl = *(const bf16x8*)&Wl[ct * 16 + lm][ko];
      acc[ct] = __builtin_amdgcn_mfma_f32_16x16x32_bf16(ah, bh, acc[ct], 0, 0, 0);
      acc[ct] = __builtin_amdgcn_mfma_f32_16x16x32_bf16(ah, bl, acc[ct], 0, 0, 0);
      acc[ct] = __builtin_amdgcn_mfma_f32_16x16x32_bf16(al, bh, acc[ct], 0, 0, 0);
    }
  }
  #pragma unroll
  for (int ct = 0; ct < 4; ct++) {
    const int col = c0 + ct * 16 + lm;
    const float bb = bias[col];
    #pragma unroll
    for (int r = 0; r < 4; r++) {
      const int row = n0 + w * 16 + quad * 4 + r;
      C[(size_t)row * NC + col] = acc[ct][r] + bb;
    }
  }
}

// generic f32 GEMM (MHA-phase): C[N x NC] = act(A[N x 128] @ W[128 x NC] + bias)
__global__ __launch_bounds__(256) void k_gemm2(const float* __restrict__ A,
                                               const float* __restrict__ W,
                                               const float* __restrict__ bias,
                                               float* __restrict__ C, int NC, int gelu) {
  __shared__ float As[128][65];
  __shared__ float Ws[128][64];
  const int t = threadIdx.x;
  const int n0 = blockIdx.y * 64, c0 = blockIdx.x * 64;
  for (int i = t; i < 2048; i += 256) {
    const int r = i & 63, k4 = (i >> 6) << 2;
    const float4 a = *(const float4*)&A[(size_t)(n0 + r) * 128 + k4];
    As[k4+0][r] = a.x; As[k4+1][r] = a.y; As[k4+2][r] = a.z; As[k4+3][r] = a.w;
  }
  for (int i = t; i < 2048; i += 256) {
    const int kk = i >> 4, c4 = (i & 15) << 2;
    *(float4*)&Ws[kk][c4] = *(const float4*)&W[(size_t)kk * NC + c0 + c4];
  }
  __syncthreads();
  const int tr = (t >> 4) << 2;
  const int tc = (t & 15) << 2;
  float acc[4][4];
  #pragma unroll
  for (int i = 0; i < 4; i++)
    #pragma unroll
    for (int j = 0; j < 4; j++) acc[i][j] = 0.f;
  #pragma unroll 8
  for (int k = 0; k < 128; k++) {
    const float4 av = *(const float4*)&As[k][tr];
    const float4 wv = *(const float4*)&Ws[k][tc];
    acc[0][0] += av.x*wv.x; acc[0][1] += av.x*wv.y; acc[0][2] += av.x*wv.z; acc[0][3] += av.x*wv.w;
    acc[1][0] += av.y*wv.x; acc[1][1] += av.y*wv.y; acc[1][2] += av.y*wv.z; acc[1][3] += av.y*wv.w;
    acc[2][0] += av.z*wv.x; acc[2][1] += av.z*wv.y; acc[2][2] += av.z*wv.z; acc[2][3] += av.z*wv.w;
    acc[3][0] += av.w*wv.x; acc[3][1] += av.w*wv.y; acc[3][2] += av.w*wv.z; acc[3][3] += av.w*wv.w;
  }
  const float4 bb = *(const float4*)&bias[c0 + tc];
  #pragma unroll
  for (int i = 0; i < 4; i++) {
    float4 v;
    v.x = acc[i][0] + bb.x; v.y = acc[i][1] + bb.y;
    v.z = acc[i][2] + bb.z; v.w = acc[i][3] + bb.w;
    if (gelu) { v.x = gelu_f(v.x); v.y = gelu_f(v.y); v.z = gelu_f(v.z); v.w = gelu_f(v.w); }
    *(float4*)&C[(size_t)(n0 + tr + i) * NC + c0 + tc] = v;
  }
}

// FUSED edge-attention + corr-GEMM + residual-LN + gelu + bf16-split, v2p:
// 1024 blocks x 256 thr (4 waves, 4 nodes/block), fully wave-private, zero
// __syncthreads. Edge loop DEPTH-2 software-pipelined: K/V/ef for edge i+1
// issued during edge i's compute (indices for i+2 prefetched ahead) ->
// 2x outstanding HBM loads per wave. XCD swizzle: graph = blockIdx&7.
__global__ __launch_bounds__(256) void k_edgepost(
    const float* __restrict__ qb, const float* __restrict__ kb,
    const float* __restrict__ vb, const float* __restrict__ qe,
    const float* __restrict__ ef, const int* __restrict__ offs,
    const int* __restrict__ elist, const int* __restrict__ eidx,
    const float* __restrict__ we_l, const float* __restrict__ skb,
    const float* __restrict__ lng, const float* __restrict__ lnb,
    float* __restrict__ h,
    unsigned short* __restrict__ hhi, unsigned short* __restrict__ hlo) {
  __shared__ float Ss[4][256];     // per-node softmax-weighted ef (wave-private)
  __shared__ float Am[4][128];     // per-node accumulators (wave-private)
  const int t = threadIdx.x;
  const int wid = t >> 6, lane = t & 63;
  const int n0 = (blockIdx.x & 7) * 512 + (blockIdx.x >> 3) * 4;
  const int n = n0 + wid;
  // ---- phase 1: edge attention (one wave per node, depth-2 pipeline) ----
  {
    const int hh = lane >> 3, s8 = lane & 7;
    const int d0 = hh * 128 + s8 * 16;
    F16U qv;
    {
      const float4* qp = (const float4*)(qb + (size_t)n * 1024 + d0);
      #pragma unroll
      for (int i = 0; i < 4; i++) qv.v4[i] = qp[i];
    }
    const float4 qe4 = *(const float4*)(qe + (size_t)n * 256 + hh * 32 + s8 * 4);
    float m = -INFINITY, z = 0.f;
    float acc[16];
    #pragma unroll
    for (int i = 0; i < 16; i++) acc[i] = 0.f;
    float sx = 0.f, sy = 0.f, sz = 0.f, sw = 0.f;
    const int e0 = offs[n], e1 = offs[n + 1];
    // pipeline state: kvC/vvC/efC hold data for edge tt; eN/sN index edge tt+1
    F16U kvC, vvC;
    float4 efC;
    int eN = 0, sN = 0;
    if (e0 < e1) {
      const int eA = elist[e0];
      const int sA = eidx[eA];
      const float4* kp = (const float4*)(kb + (size_t)sA * 1024 + d0);
      const float4* vp = (const float4*)(vb + (size_t)sA * 1024 + d0);
      #pragma unroll
      for (int i = 0; i < 4; i++) { kvC.v4[i] = kp[i]; vvC.v4[i] = vp[i]; }
      efC = *(const float4*)(ef + (size_t)eA * 32 + s8 * 4);
    }
    if (e0 + 1 < e1) { eN = elist[e0 + 1]; sN = eidx[eN]; }
    for (int tt = e0; tt < e1; tt++) {
      const F16U kv = kvC, vv = vvC;
      const float4 ef4 = efC;
      // issue next edge's loads NOW (overlap with compute below)
      if (tt + 1 < e1) {
        const float4* kp = (const float4*)(kb + (size_t)sN * 1024 + d0);
        const float4* vp = (const float4*)(vb + (size_t)sN * 1024 + d0);
        #pragma unroll
        for (int i = 0; i < 4; i++) { kvC.v4[i] = kp[i]; vvC.v4[i] = vp[i]; }
        efC = *(const float4*)(ef + (size_t)eN * 32 + s8 * 4);
        if (tt + 2 < e1) { eN = elist[tt + 2]; sN = eidx[eN]; }  // indices for i+2
      }
      float p0 = qe4.x*ef4.x + qe4.y*ef4.y;
      float p1 = qe4.z*ef4.z + qe4.w*ef4.w;
      float p2 = 0.f, p3 = 0.f;
      #pragma unroll
      for (int i = 0; i < 4; i++) {
        p0 += qv.f[i]      * kv.f[i];
        p1 += qv.f[4 + i]  * kv.f[4 + i];
        p2 += qv.f[8 + i]  * kv.f[8 + i];
        p3 += qv.f[12 + i] * kv.f[12 + i];
      }
      float p = (p0 + p1) + (p2 + p3);
      p += __shfl_xor(p, 1);
      p += __shfl_xor(p, 2);
      p += __shfl_xor(p, 4);
      const float logit = p * 0.08838834764831845f;   // 1/sqrt(128)
      if (logit > m + 8.f) {                          // deferred-max rescale
        const float f = __expf(m - logit);
        z *= f; sx *= f; sy *= f; sz *= f; sw *= f;
        #pragma unroll
        for (int i = 0; i < 16; i++) acc[i] *= f;
        m = logit;
      }
      const float w = __expf(logit - m);
      z += w;
      #pragma unroll
      for (int i = 0; i < 16; i++) acc[i] += w * vv.f[i];
      sx += w * ef4.x; sy += w * ef4.y;
      sz += w * ef4.z; sw += w * ef4.w;
    }
    const float inv = 1.f / (z + 1e-16f);
    *(float4*)&Ss[wid][hh * 32 + s8 * 4] =
        make_float4(sx * inv, sy * inv, sz * inv, sw * inv);
    F16U ov;
    #pragma unroll
    for (int i = 0; i < 16; i++) ov.f[i] = acc[i] * inv;
    #pragma unroll
    for (int mask = 8; mask <= 32; mask <<= 1)
      #pragma unroll
      for (int i = 0; i < 16; i++) ov.f[i] += __shfl_xor(ov.f[i], mask);
    if (hh == 0) {
      #pragma unroll
      for (int i = 0; i < 16; i++) ov.f[i] *= 0.125f;
      #pragma unroll
      for (int i = 0; i < 4; i++)
        *(float4*)&Am[wid][s8 * 16 + i * 4] = ov.v4[i];
    }
  }
  // ---- phase 2: corr GEMM, wave-local, float4 weights, k split by half ----
  // corr[n][c] = sum_{k<256} Ss[n][k] * we[(k&31)*1024 + (k>>5)*128 + c]
  {
    const int half = lane >> 5;          // k-half: [0,128) or [128,256)
    const int q4 = (lane & 31) << 2;     // col quad base
    float ax = 0.f, ay = 0.f, az = 0.f, aw = 0.f;
    #pragma unroll 8
    for (int i = 0; i < 128; i++) {
      const int k = half * 128 + i;
      const float4 wv = *(const float4*)&we_l[(size_t)(k & 31) * 1024 + (k >> 5) * 128 + q4];
      const float s = Ss[wid][k];
      ax += s * wv.x; ay += s * wv.y; az += s * wv.z; aw += s * wv.w;
    }
    ax += __shfl_xor(ax, 32); ay += __shfl_xor(ay, 32);
    az += __shfl_xor(az, 32); aw += __shfl_xor(aw, 32);
    if (lane < 32) {
      const size_t o = (size_t)n * 128 + q4;
      const float4 sk4 = *(const float4*)&skb[o];
      const float4 h4  = *(const float4*)&h[o];
      float4 am = *(float4*)&Am[wid][q4];
      am.x += 0.125f * ax + sk4.x + h4.x;
      am.y += 0.125f * ay + sk4.y + h4.y;
      am.z += 0.125f * az + sk4.z + h4.z;
      am.w += 0.125f * aw + sk4.w + h4.w;
      *(float4*)&Am[wid][q4] = am;
    }
  }
  // ---- phase 3: LN + gelu + bsplit (wave-private; no barrier needed) ----
  {
    const float v0 = Am[wid][lane], v1 = Am[wid][lane + 64];
    float s = v0 + v1;
    #pragma unroll
    for (int mask = 1; mask <= 32; mask <<= 1) s += __shfl_xor(s, mask);
    const float mean = s * (1.f / 128.f);
    const float d0 = v0 - mean, d1 = v1 - mean;
    float q = d0 * d0 + d1 * d1;
    #pragma unroll
    for (int mask = 1; mask <= 32; mask <<= 1) q += __shfl_xor(q, mask);
    const float rstd = 1.f / sqrtf(q * (1.f / 128.f) + 1e-5f);
    const float y0 = d0 * rstd * lng[lane] + lnb[lane];
    const float y1 = d1 * rstd * lng[lane + 64] + lnb[lane + 64];
    const float r0 = gelu_f(y0);
    const float r1 = gelu_f(y1);
    const size_t o = (size_t)n * 128 + lane;
    h[o] = r0;
    h[o + 64] = r1;
    bsplit(r0, hhi[o], hlo[o]);
    bsplit(r1, hhi[o + 64], hlo[o + 64]);
  }
}

// flash-split dense MHA: grid (ks=8, qt=2, bh=64), 256 thr, 8 KB LDS.
// K/V read strided straight from qkvm (64 B segments; L2-resident).
__global__ __launch_bounds__(256) void k_attn2b(const float* __restrict__ qkvm,
                                                float* __restrict__ pm,
                                                float* __restrict__ pz,
                                                float* __restrict__ pacc) {
  __shared__ float ks2[64][16];
  __shared__ float vs2[64][16];
  const int ksp = blockIdx.x, qt = blockIdx.y, bh = blockIdx.z;
  const int b = bh >> 3, hh = bh & 7;
  const int t = threadIdx.x;
  const size_t rbase = (size_t)(b * 512 + ksp * 64);
  {
    const int j = t >> 2, d4 = (t & 3) << 2;    // 256 threads cover 64 rows x 4 float4
    const size_t ro = (rbase + j) * 384 + hh * 16 + d4;
    *(float4*)&ks2[j][d4] = *(const float4*)&qkvm[ro + 128];
    *(float4*)&vs2[j][d4] = *(const float4*)&qkvm[ro + 256];
  }
  __syncthreads();
  const int qrow = qt * 256 + t;
  const int nq = b * 512 + qrow;
  F16U qv;
  {
    const float4* qp = (const float4*)(qkvm + (size_t)nq * 384 + hh * 16);
    #pragma unroll
    for (int i = 0; i < 4; i++) qv.v4[i] = qp[i];
  }
  float m = -INFINITY, z = 0.f;
  float acc[16];
  #pragma unroll
  for (int i = 0; i < 16; i++) acc[i] = 0.f;
  for (int j = 0; j < 64; j += 2) {
    F16U k0, k1, v0, v1;
    {
      const float4* p0 = (const float4*)ks2[j];
      const float4* p1 = (const float4*)ks2[j + 1];
      const float4* q0 = (const float4*)vs2[j];
      const float4* q1 = (const float4*)vs2[j + 1];
      #pragma unroll
      for (int i = 0; i < 4; i++) {
        k0.v4[i] = p0[i]; k1.v4[i] = p1[i];
        v0.v4[i] = q0[i]; v1.v4[i] = q1[i];
      }
    }
    float a0 = 0.f, a1 = 0.f, a2 = 0.f, a3 = 0.f;
    float b0 = 0.f, b1 = 0.f, b2 = 0.f, b3 = 0.f;
    #pragma unroll
    for (int i = 0; i < 4; i++) {
      a0 += qv.f[i]      * k0.f[i];
      a1 += qv.f[4 + i]  * k0.f[4 + i];
      a2 += qv.f[8 + i]  * k0.f[8 + i];
      a3 += qv.f[12 + i] * k0.f[12 + i];
      b0 += qv.f[i]      * k1.f[i];
      b1 += qv.f[4 + i]  * k1.f[4 + i];
      b2 += qv.f[8 + i]  * k1.f[8 + i];
      b3 += qv.f[12 + i] * k1.f[12 + i];
    }
    const float sa = ((a0 + a1) + (a2 + a3)) * 0.25f;   // 1/sqrt(16)
    const float sb = ((b0 + b1) + (b2 + b3)) * 0.25f;
    const float smax = fmaxf(sa, sb);
    if (smax > m + 8.f) {
      const float f = __expf(m - smax);
      z *= f;
      #pragma unroll
      for (int i = 0; i < 16; i++) acc[i] *= f;
      m = smax;
    }
    const float wa = __expf(sa - m);
    const float wb = __expf(sb - m);
    z += wa + wb;
    #pragma unroll
    for (int i = 0; i < 16; i++)
      acc[i] += wa * v0.f[i] + wb * v1.f[i];
  }
  const int p = (bh * 512 + qrow) * 8 + ksp;
  pm[p] = m; pz[p] = z;
  float4* pp = (float4*)&pacc[(size_t)p * 16];
  F16U ov;
  #pragma unroll
  for (int i = 0; i < 16; i++) ov.f[i] = acc[i];
  #pragma unroll
  for (int i = 0; i < 4; i++) pp[i] = ov.v4[i];
}

// FUSED tail v5: merge (8 splits) + mha_out + w1 + w2 + w3. 512 blocks x 256
// thr (4 waves), 2 rows per wave, sync-free (rows wave-private in LDS).
// Weights in ORIGINAL [k][c] layout, loaded as COALESCED float4 spanning
// (2 k-rows x 32 c-quads) per instruction; k-parity folded by shfl_xor(32).
// Each weight load serves both rows -> 320 MB fully-coalesced L2 traffic.
__global__ __launch_bounds__(256) void k_tail(
    const float* __restrict__ pm, const float* __restrict__ pz,
    const float* __restrict__ pacc,
    const float* __restrict__ mow, const float* __restrict__ mob,
    const float* __restrict__ w1, const float* __restrict__ b1,
    const float* __restrict__ w2, const float* __restrict__ b2,
    const float* __restrict__ w3, const float* __restrict__ b3,
    float* __restrict__ out) {
  __shared__ float RA[8][128];
  __shared__ float RB[8][128];
  const int t = threadIdx.x;
  const int w = t >> 6, lane = t & 63;
  const int n0 = blockIdx.x * 8;
  const int rA = w * 2, rB = w * 2 + 1;
  // stage 0: merge 8 key-splits (exact LSE) -> RA rows
  #pragma unroll
  for (int rr = 0; rr < 2; rr++) {
    const int n = n0 + w * 2 + rr;
    const int b = n >> 9, qrow = n & 511;
    #pragma unroll
    for (int half = 0; half < 2; half++) {
      const int c = lane + half * 64;
      const int hh = c >> 4, d = c & 15;
      const int base = ((b * 8 + hh) * 512 + qrow) * 8;
      float ms = pm[base];
      #pragma unroll
      for (int s = 1; s < 8; s++) ms = fmaxf(ms, pm[base + s]);
      float z = 0.f, o = 0.f;
      #pragma unroll
      for (int s = 0; s < 8; s++) {
        const float wg = __expf(pm[base + s] - ms);
        z += pz[base + s] * wg;
        o += pacc[(size_t)(base + s) * 16 + d] * wg;
      }
      RA[w * 2 + rr][c] = o / z;
    }
  }
  // stage A: RB = RA @ mow + mob  (128 -> 128)
  {
    const int kk = lane >> 5;              // k parity 0/1
    const int c4 = (lane & 31) << 2;       // output col quad
    float a0x=0.f,a0y=0.f,a0z=0.f,a0w=0.f, a1x=0.f,a1y=0.f,a1z=0.f,a1w=0.f;
    #pragma unroll 8
    for (int i = 0; i < 64; i++) {
      const int k = kk + (i << 1);
      const float4 wv = *(const float4*)&mow[(size_t)k * 128 + c4];
      const float r0 = RA[rA][k], r1 = RA[rB][k];
      a0x += r0*wv.x; a0y += r0*wv.y; a0z += r0*wv.z; a0w += r0*wv.w;
      a1x += r1*wv.x; a1y += r1*wv.y; a1z += r1*wv.z; a1w += r1*wv.w;
    }
    a0x += __shfl_xor(a0x, 32); a0y += __shfl_xor(a0y, 32);
    a0z += __shfl_xor(a0z, 32); a0w += __shfl_xor(a0w, 32);
    a1x += __shfl_xor(a1x, 32); a1y += __shfl_xor(a1y, 32);
    a1z += __shfl_xor(a1z, 32); a1w += __shfl_xor(a1w, 32);
    if (lane < 32) {
      RB[rA][c4+0] = a0x + mob[c4+0]; RB[rA][c4+1] = a0y + mob[c4+1];
      RB[rA][c4+2] = a0z + mob[c4+2]; RB[rA][c4+3] = a0w + mob[c4+3];
      RB[rB][c4+0] = a1x + mob[c4+0]; RB[rB][c4+1] = a1y + mob[c4+1];
      RB[rB][c4+2] = a1z + mob[c4+2]; RB[rB][c4+3] = a1w + mob[c4+3];
    }
  }
  // stage B: RA = gelu(RB @ w1 + b1)  (128 -> 128)
  {
    const int kk = lane >> 5;
    const int c4 = (lane & 31) << 2;
    float a0x=0.f,a0y=0.f,a0z=0.f,a0w=0.f, a1x=0.f,a1y=0.f,a1z=0.f,a1w=0.f;
    #pragma unroll 8
    for (int i = 0; i < 64; i++) {
      const int k = kk + (i << 1);
      const float4 wv = *(const float4*)&w1[(size_t)k * 128 + c4];
      const float r0 = RB[rA][k], r1 = RB[rB][k];
      a0x += r0*wv.x; a0y += r0*wv.y; a0z += r0*wv.z; a0w += r0*wv.w;
      a1x += r1*wv.x; a1y += r1*wv.y; a1z += r1*wv.z; a1w += r1*wv.w;
    }
    a0x += __shfl_xor(a0x, 32); a0y += __shfl_xor(a0y, 32);
    a0z += __shfl_xor(a0z, 32); a0w += __shfl_xor(a0w, 32);
    a1x += __shfl_xor(a1x, 32); a1y += __shfl_xor(a1y, 32);
    a1z += __shfl_xor(a1z, 32); a1w += __shfl_xor(a1w, 32);
    if (lane < 32) {
      RA[rA][c4+0] = gelu_f(a0x + b1[c4+0]); RA[rA][c4+1] = gelu_f(a0y + b1[c4+1]);
      RA[rA][c4+2] = gelu_f(a0z + b1[c4+2]); RA[rA][c4+3] = gelu_f(a0w + b1[c4+3]);
      RA[rB][c4+0] = gelu_f(a1x + b1[c4+0]); RA[rB][c4+1] = gelu_f(a1y + b1[c4+1]);
      RA[rB][c4+2] = gelu_f(a1z + b1[c4+2]); RA[rB][c4+3] = gelu_f(a1w + b1[c4+3]);
    }
  }
  // stage C: RB[:, :64] = gelu(RA @ w2 + b2)  (128 -> 64)
  {
    const int kk = lane >> 4;              // k residue 0..3
    const int c4 = (lane & 15) << 2;       // output col quad (0..60)
    float a0x=0.f,a0y=0.f,a0z=0.f,a0w=0.f, a1x=0.f,a1y=0.f,a1z=0.f,a1w=0.f;
    #pragma unroll 8
    for (int i = 0; i < 32; i++) {
      const int k = kk + (i << 2);
      const float4 wv = *(const float4*)&w2[(size_t)k * 64 + c4];
      const float r0 = RA[rA][k], r1 = RA[rB][k];
      a0x += r0*wv.x; a0y += r0*wv.y; a0z += r0*wv.z; a0w += r0*wv.w;
      a1x += r1*wv.x; a1y += r1*wv.y; a1z += r1*wv.z; a1w += r1*wv.w;
    }
    a0x += __shfl_xor(a0x, 16); a0y += __shfl_xor(a0y, 16);
    a0z += __shfl_xor(a0z, 16); a0w += __shfl_xor(a0w, 16);
    a1x += __shfl_xor(a1x, 16); a1y += __shfl_xor(a1y, 16);
    a1z += __shfl_xor(a1z, 16); a1w += __shfl_xor(a1w, 16);
    a0x += __shfl_xor(a0x, 32); a0y += __shfl_xor(a0y, 32);
    a0z += __shfl_xor(a0z, 32); a0w += __shfl_xor(a0w, 32);
    a1x += __shfl_xor(a1x, 32); a1y += __shfl_xor(a1y, 32);
    a1z += __shfl_xor(a1z, 32); a1w += __shfl_xor(a1w, 32);
    if (lane < 16) {
      RB[rA][c4+0] = gelu_f(a0x + b2[c4+0]); RB[rA][c4+1] = gelu_f(a0y + b2[c4+1]);
      RB[rA][c4+2] = gelu_f(a0z + b2[c4+2]); RB[rA][c4+3] = gelu_f(a0w + b2[c4+3]);
      RB[rB][c4+0] = gelu_f(a1x + b2[c4+0]); RB[rB][c4+1] = gelu_f(a1y + b2[c4+1]);
      RB[rB][c4+2] = gelu_f(a1z + b2[c4+2]); RB[rB][c4+3] = gelu_f(a1w + b2[c4+3]);
    }
  }
  // stage D: out = RB[:, :64] @ w3 + b3   (64 -> 3)
  if (lane < 3) {
    #pragma unroll
    for (int rr = 0; rr < 2; rr++) {
      const int row = w * 2 + rr;
      float s = b3[lane];
      for (int c = 0; c < 64; c++) s += RB[row][c] * w3[c * 3 + lane];
      out[(size_t)(n0 + row) * 3 + lane] = s;
    }
  }
}

extern "C" void kernel_launch(void* const* d_in, const int* in_sizes, int n_in,
                              void* d_out, int out_size, void* d_ws, size_t ws_size,
                              hipStream_t stream) {
  const int*   x         = (const int*)d_in[0];
  const int*   eidx      = (const int*)d_in[1];
  const float* edge_attr = (const float*)d_in[2];
  const float* atom_emb  = (const float*)d_in[4];
  const float* edge_w    = (const float*)d_in[5];
  const float* edge_b    = (const float*)d_in[6];
  const float* wq        = (const float*)d_in[7];
  const float* bq        = (const float*)d_in[8];
  const float* wk        = (const float*)d_in[9];
  const float* bk        = (const float*)d_in[10];
  const float* wv        = (const float*)d_in[11];
  const float* bv        = (const float*)d_in[12];
  const float* we        = (const float*)d_in[13];
  const float* wskip     = (const float*)d_in[14];
  const float* bskip     = (const float*)d_in[15];
  const float* ln_g      = (const float*)d_in[16];
  const float* ln_b      = (const float*)d_in[17];
  const float* mha_in_w  = (const float*)d_in[18];
  const float* mha_in_b  = (const float*)d_in[19];
  const float* mha_out_w = (const float*)d_in[20];
  const float* mha_out_b = (const float*)d_in[21];
  const float* w1        = (const float*)d_in[22];
  const float* b1        = (const float*)d_in[23];
  const float* w2        = (const float*)d_in[24];
  const float* b2        = (const float*)d_in[25];
  const float* w3        = (const float*)d_in[26];
  const float* b3        = (const float*)d_in[27];

  float* ws   = (float*)d_ws;
  float* h    = ws;
  float* ef   = h + 524288;
  float* qb   = ef + 524288;
  float* kb   = qb + 4194304;
  float* vb   = kb + 4194304;
  float* qe   = vb + 4194304;
  float* big  = qe + 1048576;       // 4194304 floats, subdivided:
  float* skb  = big + 1048576;      //   524288
  // split-bf16 buffers carved from the tail of big (5242880 shorts available):
  unsigned short* hhi  = (unsigned short*)(big + 1572864);   // 524288 shorts
  unsigned short* hlo  = hhi + 524288;                       // 524288 shorts
  unsigned short* wthi = hlo + 524288;                       // 1769472 shorts
  unsigned short* wtlo = wthi + 1769472;                     // 1769472 shorts (= 4587520 total, fits)
  float* sbuf = big + 4194304;      // 1048576 (scratch region)
  // MHA-phase aliases (layer-phase buffers dead by then)
  float* qkvm = qb;                 // N*384
  float* pm   = sbuf;               // 262144 (32768 rows x 8 splits)
  float* pz   = sbuf + 262144;      // 262144
  float* pacc = big;                // 4194304 (layer-phase big contents dead)
  int* counts = (int*)(sbuf + 1048576);
  int* offs   = counts + 4100;
  int* heads  = offs + 4100;        // (unused; kept for layout stability)
  int* elist  = heads + 4100;
  float* bqe  = (float*)(elist + 16384);   // 1024 floats

  k_init<<<2048, 256, 0, stream>>>(x, atom_emb, edge_attr, edge_w, edge_b, h, ef, counts,
                                   hhi, hlo);
  k_hist<<<64, 256, 0, stream>>>(eidx, counts);
  k_scan2<<<1, 1024, 0, stream>>>(counts, offs, eidx, elist);
  k_wcvt<<<dim3(16, 2, 16), 256, 0, stream>>>(wq, wk, wv, wskip, wthi, wtlo);
  k_wqe<<<32, 256, 0, stream>>>(wq, bq, we, wthi, wtlo, bqe);

  for (int i = 0; i < NLAYERS; i++) {
    const float* bq_i  = bq + (size_t)i * 1024;
    const float* bk_i  = bk + (size_t)i * 1024;
    const float* bv_i  = bv + (size_t)i * 1024;
    const float* we_i  = we + (size_t)i * 32768;
    const float* bsk_i = bskip + (size_t)i * 128;
    const float* g_i   = ln_g + (size_t)i * 128;
    const float* b_i   = ln_b + (size_t)i * 128;
    const unsigned short* wth_i = wthi + (size_t)i * WT_STRIDE;
    const unsigned short* wtl_i = wtlo + (size_t)i * WT_STRIDE;

    k_mfqkv<<<dim3(54, 64), 256, 0, stream>>>(hhi, hlo, wth_i, wtl_i,
                                              bq_i, bk_i, bv_i, bsk_i, bqe + i * 256,
                                              qb, kb, vb, skb, qe);
    k_edgepost<<<1024, 256, 0, stream>>>(qb, kb, vb, qe, ef, offs, elist, eidx,
                                         we_i, skb, g_i, b_i, h, hhi, hlo);
  }

  k_gemm2<<<dim3(6, 64), 256, 0, stream>>>(h, mha_in_w, mha_in_b, qkvm, 384, 0);
  k_attn2b<<<dim3(8, 2, 64), 256, 0, stream>>>(qkvm, pm, pz, pacc);
  k_tail<<<512, 256, 0, stream>>>(pm, pz, pacc,
                                  mha_out_w, mha_out_b, w1, b1, w2, b2, w3, b3,
                                  (float*)d_out);
}

// Round 15
// 454.475 us; speedup vs baseline: 1.0481x; 1.0481x over previous
//
#include <hip/hip_runtime.h>
#include <hip/hip_bf16.h>
#include <math.h>

#define NN 4096
#define NE 16384
#define NLAYERS 4

// per-layer short layout of split weights:
// [wq_t 131072 | wk_t 131072 | wv_t 131072 | wsk_t 16384 | wqe_t 32768] = 442368
#define WT_STRIDE 442368

typedef __attribute__((ext_vector_type(8))) short bf16x8;
typedef __attribute__((ext_vector_type(4))) float floatx4;

__device__ __forceinline__ float gelu_f(float x) {
  return 0.5f * x * (1.0f + erff(x * 0.70710678118654752440f));
}

// split f32 into hi+lo bf16 (hi = RN(a), lo = RN(a - hi)); hi+lo accurate to ~2^-17
__device__ __forceinline__ void bsplit(float a, unsigned short& hi, unsigned short& lo) {
  __hip_bfloat16 h16 = __float2bfloat16(a);
  hi = *(unsigned short*)&h16;
  const float r = a - __bfloat162float(h16);
  __hip_bfloat16 l16 = __float2bfloat16(r);
  lo = *(unsigned short*)&l16;
}

union F16U { float4 v4[4]; float f[16]; };

__global__ void k_init(const int* __restrict__ x, const float* __restrict__ atom_emb,
                       const float* __restrict__ edge_attr, const float* __restrict__ edge_w,
                       const float* __restrict__ edge_b, float* __restrict__ h,
                       float* __restrict__ ef, int* __restrict__ counts,
                       unsigned short* __restrict__ hhi, unsigned short* __restrict__ hlo) {
  const int idx = blockIdx.x * 256 + threadIdx.x;      // 0..524287 (= NN*128 = NE*32)
  const float hv = atom_emb[x[idx >> 7] * 128 + (idx & 127)];
  h[idx] = hv;
  bsplit(hv, hhi[idx], hlo[idx]);
  ef[idx] = edge_attr[idx >> 5] * edge_w[idx & 31] + edge_b[idx & 31];
  if (idx < NN) counts[idx] = 0;
}

__global__ void k_hist(const int* __restrict__ eidx, int* __restrict__ counts) {
  const int e = blockIdx.x * 256 + threadIdx.x;
  if (e < NE) atomicAdd(&counts[eidx[NE + e]], 1);
}

// scan + scatter fused: prefix-sum counts -> offs; bucket edges via LDS atomics.
__global__ void k_scan2(const int* __restrict__ counts, int* __restrict__ offs,
                        const int* __restrict__ eidx, int* __restrict__ elist) {
  __shared__ int tmp[1024];
  __shared__ int sheads[4096];
  const int t = threadIdx.x;
  const int c0 = counts[t*4], c1 = counts[t*4+1], c2 = counts[t*4+2], c3 = counts[t*4+3];
  const int s = c0 + c1 + c2 + c3;
  tmp[t] = s; __syncthreads();
  for (int off = 1; off < 1024; off <<= 1) {
    int v = (t >= off) ? tmp[t - off] : 0;
    __syncthreads();
    tmp[t] += v;
    __syncthreads();
  }
  int base = tmp[t] - s;
  offs[t*4]   = base;                sheads[t*4]   = base;
  offs[t*4+1] = base + c0;           sheads[t*4+1] = base + c0;
  offs[t*4+2] = base + c0 + c1;      sheads[t*4+2] = base + c0 + c1;
  offs[t*4+3] = base + c0 + c1 + c2; sheads[t*4+3] = base + c0 + c1 + c2;
  if (t == 1023) offs[NN] = tmp[1023];
  __syncthreads();
  for (int e = t; e < NE; e += 1024) {
    const int p = atomicAdd(&sheads[eidx[NE + e]], 1);
    elist[p] = e;
  }
}

// one-time: split + transpose all layer weights -> wthi/wtlo[n][k] bf16
__global__ __launch_bounds__(256) void k_wcvt(
    const float* __restrict__ wq, const float* __restrict__ wk,
    const float* __restrict__ wv, const float* __restrict__ wsk,
    unsigned short* __restrict__ wthi, unsigned short* __restrict__ wtlo) {
  const int z = blockIdx.z;            // layer*4 + mat
  const int layer = z >> 2, mat = z & 3;
  int NC; const float* W; int woff;
  if (mat == 0)      { NC = 1024; W = wq  + (size_t)layer * 131072; woff = 0; }
  else if (mat == 1) { NC = 1024; W = wk  + (size_t)layer * 131072; woff = 131072; }
  else if (mat == 2) { NC = 1024; W = wv  + (size_t)layer * 131072; woff = 262144; }
  else               { NC = 128;  W = wsk + (size_t)layer * 16384;  woff = 393216; }
  const int c0 = blockIdx.x * 64;
  if (c0 >= NC) return;
  const int k0 = blockIdx.y * 64;
  __shared__ unsigned short th[64][65], tl[64][65];
  const int t = threadIdx.x;
  for (int i = t; i < 4096; i += 256) {
    const int kk = i >> 6, c = i & 63;
    bsplit(W[(size_t)(k0 + kk) * NC + c0 + c], th[kk][c], tl[kk][c]);
  }
  __syncthreads();
  unsigned short* oh = wthi + (size_t)layer * WT_STRIDE + woff;
  unsigned short* ol = wtlo + (size_t)layer * WT_STRIDE + woff;
  for (int i = t; i < 4096; i += 256) {
    const int n = i >> 6, k = i & 63;
    oh[(size_t)(c0 + n) * 128 + k0 + k] = th[k][n];
    ol[(size_t)(c0 + n) * 128 + k0 + k] = tl[k][n];
  }
}

// one-time: composed qe weight.  qe = h @ Wqe_t^T + bqe where
// Wqe_t[j=hh*32+c][d] = sum_dd wq[d][hh*128+dd] * we[c][hh*128+dd]
// bqe[j]             = sum_dd bq[hh*128+dd]     * we[c][hh*128+dd]
__global__ __launch_bounds__(256) void k_wqe(
    const float* __restrict__ wq, const float* __restrict__ bq,
    const float* __restrict__ we, unsigned short* __restrict__ wthi,
    unsigned short* __restrict__ wtlo, float* __restrict__ bqe) {
  const int layer = blockIdx.x >> 3, hh = blockIdx.x & 7;
  const float* wq_l = wq + (size_t)layer * 131072;   // [128][1024]
  const float* we_l = we + (size_t)layer * 32768;    // [32][1024]
  const float* bq_l = bq + (size_t)layer * 1024;
  __shared__ float wqS[128][132];   // wqS[d][dd]
  __shared__ float weS[32][132];    // weS[c][dd]
  const int t = threadIdx.x;
  for (int i = t; i < 4096; i += 256) {               // 128 rows x 32 float4
    const int d = i >> 5, dd4 = (i & 31) << 2;
    *(float4*)&wqS[d][dd4] = *(const float4*)&wq_l[(size_t)d * 1024 + hh * 128 + dd4];
  }
  for (int i = t; i < 1024; i += 256) {               // 32 rows x 32 float4
    const int c = i >> 5, dd4 = (i & 31) << 2;
    *(float4*)&weS[c][dd4] = *(const float4*)&we_l[(size_t)c * 1024 + hh * 128 + dd4];
  }
  __syncthreads();
  const int d = t & 127, cg = t >> 7;                 // each thread: 16 c values
  float acc[16];
  #pragma unroll
  for (int cc = 0; cc < 16; cc++) acc[cc] = 0.f;
  for (int dd = 0; dd < 128; dd++) {
    const float a = wqS[d][dd];
    #pragma unroll
    for (int cc = 0; cc < 16; cc++)
      acc[cc] += a * weS[cg * 16 + cc][dd];
  }
  unsigned short* oh = wthi + (size_t)layer * WT_STRIDE + 409600;
  unsigned short* ol = wtlo + (size_t)layer * WT_STRIDE + 409600;
  #pragma unroll
  for (int cc = 0; cc < 16; cc++) {
    const int j = hh * 32 + cg * 16 + cc;
    unsigned short hi, lo;
    bsplit(acc[cc], hi, lo);
    oh[(size_t)j * 128 + d] = hi;
    ol[(size_t)j * 128 + d] = lo;
  }
  if (t < 32) {
    float s = 0.f;
    for (int dd = 0; dd < 128; dd++) s += bq_l[hh * 128 + dd] * weS[t][dd];
    bqe[layer * 256 + hh * 32 + t] = s;
  }
}

// fused q/k/v/skip/qe GEMM via split-bf16 MFMA (3 passes: hi*hi + hi*lo + lo*hi).
// single grid: x in [0,54) spans all 5 output matrices' 64-col tiles.
// K and V are written INTERLEAVED into kvb (stride 2048: K at +0, V at +1024)
// so k_edgepost gathers both rows from one 8 KB region (page locality).
__global__ __launch_bounds__(256) void k_mfqkv(
    const unsigned short* __restrict__ hhi, const unsigned short* __restrict__ hlo,
    const unsigned short* __restrict__ wth, const unsigned short* __restrict__ wtl,
    const float* __restrict__ bq, const float* __restrict__ bk,
    const float* __restrict__ bv, const float* __restrict__ bsk,
    const float* __restrict__ bqe_l,
    float* __restrict__ qb, float* __restrict__ kvb,
    float* __restrict__ skb, float* __restrict__ qeb) {
  const int xb = blockIdx.x;
  int NC; const float* bias; float* C; int woff; int c0; int ldc;
  if (xb < 16)      { NC = 1024; bias = bq;    C = qb;         woff = 0;      c0 = xb * 64;      ldc = 1024; }
  else if (xb < 32) { NC = 1024; bias = bk;    C = kvb;        woff = 131072; c0 = (xb-16) * 64; ldc = 2048; }
  else if (xb < 48) { NC = 1024; bias = bv;    C = kvb + 1024; woff = 262144; c0 = (xb-32) * 64; ldc = 2048; }
  else if (xb < 50) { NC = 128;  bias = bsk;   C = skb;        woff = 393216; c0 = (xb-48) * 64; ldc = 128; }
  else              { NC = 256;  bias = bqe_l; C = qeb;        woff = 409600; c0 = (xb-50) * 64; ldc = 256; }
  __shared__ unsigned short Ah[64][136], Al[64][136], Wh[64][136], Wl[64][136];
  const int t = threadIdx.x;
  const int n0 = blockIdx.y * 64;
  for (int i = t; i < 1024; i += 256) {
    const int r = i >> 4, c8 = (i & 15) << 3;
    *(uint4*)&Ah[r][c8] = *(const uint4*)&hhi[(size_t)(n0 + r) * 128 + c8];
    *(uint4*)&Al[r][c8] = *(const uint4*)&hlo[(size_t)(n0 + r) * 128 + c8];
    *(uint4*)&Wh[r][c8] = *(const uint4*)&wth[woff + (size_t)(c0 + r) * 128 + c8];
    *(uint4*)&Wl[r][c8] = *(const uint4*)&wtl[woff + (size_t)(c0 + r) * 128 + c8];
  }
  __syncthreads();
  const int w = t >> 6, l = t & 63;
  const int quad = l >> 4, lm = l & 15;
  floatx4 acc[4] = {{0.f,0.f,0.f,0.f},{0.f,0.f,0.f,0.f},{0.f,0.f,0.f,0.f},{0.f,0.f,0.f,0.f}};
  #pragma unroll
  for (int kc = 0; kc < 4; kc++) {
    const int ko = kc * 32 + quad * 8;
    const bf16x8 ah = *(const bf16x8*)&Ah[w * 16 + lm][ko];
    const bf16x8 al = *(const bf16x8*)&Al[w * 16 + lm][ko];
    #pragma unroll
    for (int ct = 0; ct < 4; ct++) {
      const bf16x8 bh = *(const bf16x8*)&Wh[ct * 16 + lm][ko];
      const bf16x8 bl = *(const bf16x8*)&Wl[ct * 16 + lm][ko];
      acc[ct] = __builtin_amdgcn_mfma_f32_16x16x32_bf16(ah, bh, acc[ct], 0, 0, 0);
      acc[ct] = __builtin_amdgcn_mfma_f32_16x16x32_bf16(ah, bl, acc[ct], 0, 0, 0);
      acc[ct] = __builtin_amdgcn_mfma_f32_16x16x32_bf16(al, bh, acc[ct], 0, 0, 0);
    }
  }
  #pragma unroll
  for (int ct = 0; ct < 4; ct++) {
    const int col = c0 + ct * 16 + lm;
    const float bb = bias[col];
    #pragma unroll
    for (int r = 0; r < 4; r++) {
      const int row = n0 + w * 16 + quad * 4 + r;
      C[(size_t)row * ldc + col] = acc[ct][r] + bb;
    }
  }
}

// generic f32 GEMM (MHA-phase): C[N x NC] = act(A[N x 128] @ W[128 x NC] + bias)
__global__ __launch_bounds__(256) void k_gemm2(const float* __restrict__ A,
                                               const float* __restrict__ W,
                                               const float* __restrict__ bias,
                                               float* __restrict__ C, int NC, int gelu) {
  __shared__ float As[128][65];
  __shared__ float Ws[128][64];
  const int t = threadIdx.x;
  const int n0 = blockIdx.y * 64, c0 = blockIdx.x * 64;
  for (int i = t; i < 2048; i += 256) {
    const int r = i & 63, k4 = (i >> 6) << 2;
    const float4 a = *(const float4*)&A[(size_t)(n0 + r) * 128 + k4];
    As[k4+0][r] = a.x; As[k4+1][r] = a.y; As[k4+2][r] = a.z; As[k4+3][r] = a.w;
  }
  for (int i = t; i < 2048; i += 256) {
    const int kk = i >> 4, c4 = (i & 15) << 2;
    *(float4*)&Ws[kk][c4] = *(const float4*)&W[(size_t)kk * NC + c0 + c4];
  }
  __syncthreads();
  const int tr = (t >> 4) << 2;
  const int tc = (t & 15) << 2;
  float acc[4][4];
  #pragma unroll
  for (int i = 0; i < 4; i++)
    #pragma unroll
    for (int j = 0; j < 4; j++) acc[i][j] = 0.f;
  #pragma unroll 8
  for (int k = 0; k < 128; k++) {
    const float4 av = *(const float4*)&As[k][tr];
    const float4 wv = *(const float4*)&Ws[k][tc];
    acc[0][0] += av.x*wv.x; acc[0][1] += av.x*wv.y; acc[0][2] += av.x*wv.z; acc[0][3] += av.x*wv.w;
    acc[1][0] += av.y*wv.x; acc[1][1] += av.y*wv.y; acc[1][2] += av.y*wv.z; acc[1][3] += av.y*wv.w;
    acc[2][0] += av.z*wv.x; acc[2][1] += av.z*wv.y; acc[2][2] += av.z*wv.z; acc[2][3] += av.z*wv.w;
    acc[3][0] += av.w*wv.x; acc[3][1] += av.w*wv.y; acc[3][2] += av.w*wv.z; acc[3][3] += av.w*wv.w;
  }
  const float4 bb = *(const float4*)&bias[c0 + tc];
  #pragma unroll
  for (int i = 0; i < 4; i++) {
    float4 v;
    v.x = acc[i][0] + bb.x; v.y = acc[i][1] + bb.y;
    v.z = acc[i][2] + bb.z; v.w = acc[i][3] + bb.w;
    if (gelu) { v.x = gelu_f(v.x); v.y = gelu_f(v.y); v.z = gelu_f(v.z); v.w = gelu_f(v.w); }
    *(float4*)&C[(size_t)(n0 + tr + i) * NC + c0 + tc] = v;
  }
}

// FUSED edge-attention + corr-GEMM + residual-LN + gelu + bf16-split (round-12
// champion structure): 1024 blocks x 256 thr (4 waves, 4 nodes/block), fully
// wave-private, zero __syncthreads; index-prefetch only. K/V read from the
// INTERLEAVED kvb (one 8 KB region per edge). XCD swizzle: graph = blockIdx&7.
__global__ __launch_bounds__(256) void k_edgepost(
    const float* __restrict__ qb, const float* __restrict__ kvb,
    const float* __restrict__ qe,
    const float* __restrict__ ef, const int* __restrict__ offs,
    const int* __restrict__ elist, const int* __restrict__ eidx,
    const float* __restrict__ we_l, const float* __restrict__ skb,
    const float* __restrict__ lng, const float* __restrict__ lnb,
    float* __restrict__ h,
    unsigned short* __restrict__ hhi, unsigned short* __restrict__ hlo) {
  __shared__ float Ss[4][256];     // per-node softmax-weighted ef (wave-private)
  __shared__ float Am[4][128];     // per-node accumulators (wave-private)
  const int t = threadIdx.x;
  const int wid = t >> 6, lane = t & 63;
  const int n0 = (blockIdx.x & 7) * 512 + (blockIdx.x >> 3) * 4;
  const int n = n0 + wid;
  // ---- phase 1: edge attention (one wave per node, index prefetch) ----
  {
    const int hh = lane >> 3, s8 = lane & 7;
    const int d0 = hh * 128 + s8 * 16;
    F16U qv;
    {
      const float4* qp = (const float4*)(qb + (size_t)n * 1024 + d0);
      #pragma unroll
      for (int i = 0; i < 4; i++) qv.v4[i] = qp[i];
    }
    const float4 qe4 = *(const float4*)(qe + (size_t)n * 256 + hh * 32 + s8 * 4);
    float m = -INFINITY, z = 0.f;
    float acc[16];
    #pragma unroll
    for (int i = 0; i < 16; i++) acc[i] = 0.f;
    float sx = 0.f, sy = 0.f, sz = 0.f, sw = 0.f;
    const int e0 = offs[n], e1 = offs[n + 1];
    int ecur = 0, scur = 0;
    if (e0 < e1) { ecur = elist[e0]; scur = eidx[ecur]; }
    for (int tt = e0; tt < e1; tt++) {
      F16U kv, vv;
      {
        const float4* kp = (const float4*)(kvb + (size_t)scur * 2048 + d0);
        const float4* vp = (const float4*)(kvb + (size_t)scur * 2048 + 1024 + d0);
        #pragma unroll
        for (int i = 0; i < 4; i++) { kv.v4[i] = kp[i]; vv.v4[i] = vp[i]; }
      }
      const float4 ef4 = *(const float4*)(ef + (size_t)ecur * 32 + s8 * 4);
      // prefetch next edge's indices while current math runs
      if (tt + 1 < e1) { ecur = elist[tt + 1]; scur = eidx[ecur]; }
      float p0 = qe4.x*ef4.x + qe4.y*ef4.y;
      float p1 = qe4.z*ef4.z + qe4.w*ef4.w;
      float p2 = 0.f, p3 = 0.f;
      #pragma unroll
      for (int i = 0; i < 4; i++) {
        p0 += qv.f[i]      * kv.f[i];
        p1 += qv.f[4 + i]  * kv.f[4 + i];
        p2 += qv.f[8 + i]  * kv.f[8 + i];
        p3 += qv.f[12 + i] * kv.f[12 + i];
      }
      float p = (p0 + p1) + (p2 + p3);
      p += __shfl_xor(p, 1);
      p += __shfl_xor(p, 2);
      p += __shfl_xor(p, 4);
      const float logit = p * 0.08838834764831845f;   // 1/sqrt(128)
      if (logit > m + 8.f) {                          // deferred-max rescale
        const float f = __expf(m - logit);
        z *= f; sx *= f; sy *= f; sz *= f; sw *= f;
        #pragma unroll
        for (int i = 0; i < 16; i++) acc[i] *= f;
        m = logit;
      }
      const float w = __expf(logit - m);
      z += w;
      #pragma unroll
      for (int i = 0; i < 16; i++) acc[i] += w * vv.f[i];
      sx += w * ef4.x; sy += w * ef4.y;
      sz += w * ef4.z; sw += w * ef4.w;
    }
    const float inv = 1.f / (z + 1e-16f);
    *(float4*)&Ss[wid][hh * 32 + s8 * 4] =
        make_float4(sx * inv, sy * inv, sz * inv, sw * inv);
    F16U ov;
    #pragma unroll
    for (int i = 0; i < 16; i++) ov.f[i] = acc[i] * inv;
    #pragma unroll
    for (int mask = 8; mask <= 32; mask <<= 1)
      #pragma unroll
      for (int i = 0; i < 16; i++) ov.f[i] += __shfl_xor(ov.f[i], mask);
    if (hh == 0) {
      #pragma unroll
      for (int i = 0; i < 16; i++) ov.f[i] *= 0.125f;
      #pragma unroll
      for (int i = 0; i < 4; i++)
        *(float4*)&Am[wid][s8 * 16 + i * 4] = ov.v4[i];
    }
  }
  // ---- phase 2: corr GEMM, wave-local, float4 weights, k split by half ----
  // corr[n][c] = sum_{k<256} Ss[n][k] * we[(k&31)*1024 + (k>>5)*128 + c]
  {
    const int half = lane >> 5;          // k-half: [0,128) or [128,256)
    const int q4 = (lane & 31) << 2;     // col quad base
    float ax = 0.f, ay = 0.f, az = 0.f, aw = 0.f;
    #pragma unroll 8
    for (int i = 0; i < 128; i++) {
      const int k = half * 128 + i;
      const float4 wv = *(const float4*)&we_l[(size_t)(k & 31) * 1024 + (k >> 5) * 128 + q4];
      const float s = Ss[wid][k];
      ax += s * wv.x; ay += s * wv.y; az += s * wv.z; aw += s * wv.w;
    }
    ax += __shfl_xor(ax, 32); ay += __shfl_xor(ay, 32);
    az += __shfl_xor(az, 32); aw += __shfl_xor(aw, 32);
    if (lane < 32) {
      const size_t o = (size_t)n * 128 + q4;
      const float4 sk4 = *(const float4*)&skb[o];
      const float4 h4  = *(const float4*)&h[o];
      float4 am = *(float4*)&Am[wid][q4];
      am.x += 0.125f * ax + sk4.x + h4.x;
      am.y += 0.125f * ay + sk4.y + h4.y;
      am.z += 0.125f * az + sk4.z + h4.z;
      am.w += 0.125f * aw + sk4.w + h4.w;
      *(float4*)&Am[wid][q4] = am;
    }
  }
  // ---- phase 3: LN + gelu + bsplit (wave-private; no barrier needed) ----
  {
    const float v0 = Am[wid][lane], v1 = Am[wid][lane + 64];
    float s = v0 + v1;
    #pragma unroll
    for (int mask = 1; mask <= 32; mask <<= 1) s += __shfl_xor(s, mask);
    const float mean = s * (1.f / 128.f);
    const float d0 = v0 - mean, d1 = v1 - mean;
    float q = d0 * d0 + d1 * d1;
    #pragma unroll
    for (int mask = 1; mask <= 32; mask <<= 1) q += __shfl_xor(q, mask);
    const float rstd = 1.f / sqrtf(q * (1.f / 128.f) + 1e-5f);
    const float y0 = d0 * rstd * lng[lane] + lnb[lane];
    const float y1 = d1 * rstd * lng[lane + 64] + lnb[lane + 64];
    const float r0 = gelu_f(y0);
    const float r1 = gelu_f(y1);
    const size_t o = (size_t)n * 128 + lane;
    h[o] = r0;
    h[o + 64] = r1;
    bsplit(r0, hhi[o], hlo[o]);
    bsplit(r1, hhi[o + 64], hlo[o + 64]);
  }
}

// flash-split dense MHA: grid (ks=8, qt=2, bh=64), 256 thr, 8 KB LDS.
// K/V read strided straight from qkvm (64 B segments; L2-resident).
__global__ __launch_bounds__(256) void k_attn2b(const float* __restrict__ qkvm,
                                                float* __restrict__ pm,
                                                float* __restrict__ pz,
                                                float* __restrict__ pacc) {
  __shared__ float ks2[64][16];
  __shared__ float vs2[64][16];
  const int ksp = blockIdx.x, qt = blockIdx.y, bh = blockIdx.z;
  const int b = bh >> 3, hh = bh & 7;
  const int t = threadIdx.x;
  const size_t rbase = (size_t)(b * 512 + ksp * 64);
  {
    const int j = t >> 2, d4 = (t & 3) << 2;    // 256 threads cover 64 rows x 4 float4
    const size_t ro = (rbase + j) * 384 + hh * 16 + d4;
    *(float4*)&ks2[j][d4] = *(const float4*)&qkvm[ro + 128];
    *(float4*)&vs2[j][d4] = *(const float4*)&qkvm[ro + 256];
  }
  __syncthreads();
  const int qrow = qt * 256 + t;
  const int nq = b * 512 + qrow;
  F16U qv;
  {
    const float4* qp = (const float4*)(qkvm + (size_t)nq * 384 + hh * 16);
    #pragma unroll
    for (int i = 0; i < 4; i++) qv.v4[i] = qp[i];
  }
  float m = -INFINITY, z = 0.f;
  float acc[16];
  #pragma unroll
  for (int i = 0; i < 16; i++) acc[i] = 0.f;
  for (int j = 0; j < 64; j += 2) {
    F16U k0, k1, v0, v1;
    {
      const float4* p0 = (const float4*)ks2[j];
      const float4* p1 = (const float4*)ks2[j + 1];
      const float4* q0 = (const float4*)vs2[j];
      const float4* q1 = (const float4*)vs2[j + 1];
      #pragma unroll
      for (int i = 0; i < 4; i++) {
        k0.v4[i] = p0[i]; k1.v4[i] = p1[i];
        v0.v4[i] = q0[i]; v1.v4[i] = q1[i];
      }
    }
    float a0 = 0.f, a1 = 0.f, a2 = 0.f, a3 = 0.f;
    float b0 = 0.f, b1 = 0.f, b2 = 0.f, b3 = 0.f;
    #pragma unroll
    for (int i = 0; i < 4; i++) {
      a0 += qv.f[i]      * k0.f[i];
      a1 += qv.f[4 + i]  * k0.f[4 + i];
      a2 += qv.f[8 + i]  * k0.f[8 + i];
      a3 += qv.f[12 + i] * k0.f[12 + i];
      b0 += qv.f[i]      * k1.f[i];
      b1 += qv.f[4 + i]  * k1.f[4 + i];
      b2 += qv.f[8 + i]  * k1.f[8 + i];
      b3 += qv.f[12 + i] * k1.f[12 + i];
    }
    const float sa = ((a0 + a1) + (a2 + a3)) * 0.25f;   // 1/sqrt(16)
    const float sb = ((b0 + b1) + (b2 + b3)) * 0.25f;
    const float smax = fmaxf(sa, sb);
    if (smax > m + 8.f) {
      const float f = __expf(m - smax);
      z *= f;
      #pragma unroll
      for (int i = 0; i < 16; i++) acc[i] *= f;
      m = smax;
    }
    const float wa = __expf(sa - m);
    const float wb = __expf(sb - m);
    z += wa + wb;
    #pragma unroll
    for (int i = 0; i < 16; i++)
      acc[i] += wa * v0.f[i] + wb * v1.f[i];
  }
  const int p = (bh * 512 + qrow) * 8 + ksp;
  pm[p] = m; pz[p] = z;
  float4* pp = (float4*)&pacc[(size_t)p * 16];
  F16U ov;
  #pragma unroll
  for (int i = 0; i < 16; i++) ov.f[i] = acc[i];
  #pragma unroll
  for (int i = 0; i < 4; i++) pp[i] = ov.v4[i];
}

// FUSED tail v5: merge (8 splits) + mha_out + w1 + w2 + w3. 512 blocks x 256
// thr (4 waves), 2 rows per wave, sync-free (rows wave-private in LDS).
// Weights in ORIGINAL [k][c] layout, loaded as COALESCED float4 spanning
// (2 k-rows x 32 c-quads) per instruction; k-parity folded by shfl_xor(32).
// Each weight load serves both rows -> 320 MB fully-coalesced L2 traffic.
__global__ __launch_bounds__(256) void k_tail(
    const float* __restrict__ pm, const float* __restrict__ pz,
    const float* __restrict__ pacc,
    const float* __restrict__ mow, const float* __restrict__ mob,
    const float* __restrict__ w1, const float* __restrict__ b1,
    const float* __restrict__ w2, const float* __restrict__ b2,
    const float* __restrict__ w3, const float* __restrict__ b3,
    float* __restrict__ out) {
  __shared__ float RA[8][128];
  __shared__ float RB[8][128];
  const int t = threadIdx.x;
  const int w = t >> 6, lane = t & 63;
  const int n0 = blockIdx.x * 8;
  const int rA = w * 2, rB = w * 2 + 1;
  // stage 0: merge 8 key-splits (exact LSE) -> RA rows
  #pragma unroll
  for (int rr = 0; rr < 2; rr++) {
    const int n = n0 + w * 2 + rr;
    const int b = n >> 9, qrow = n & 511;
    #pragma unroll
    for (int half = 0; half < 2; half++) {
      const int c = lane + half * 64;
      const int hh = c >> 4, d = c & 15;
      const int base = ((b * 8 + hh) * 512 + qrow) * 8;
      float ms = pm[base];
      #pragma unroll
      for (int s = 1; s < 8; s++) ms = fmaxf(ms, pm[base + s]);
      float z = 0.f, o = 0.f;
      #pragma unroll
      for (int s = 0; s < 8; s++) {
        const float wg = __expf(pm[base + s] - ms);
        z += pz[base + s] * wg;
        o += pacc[(size_t)(base + s) * 16 + d] * wg;
      }
      RA[w * 2 + rr][c] = o / z;
    }
  }
  // stage A: RB = RA @ mow + mob  (128 -> 128)
  {
    const int kk = lane >> 5;              // k parity 0/1
    const int c4 = (lane & 31) << 2;       // output col quad
    float a0x=0.f,a0y=0.f,a0z=0.f,a0w=0.f, a1x=0.f,a1y=0.f,a1z=0.f,a1w=0.f;
    #pragma unroll 8
    for (int i = 0; i < 64; i++) {
      const int k = kk + (i << 1);
      const float4 wv = *(const float4*)&mow[(size_t)k * 128 + c4];
      const float r0 = RA[rA][k], r1 = RA[rB][k];
      a0x += r0*wv.x; a0y += r0*wv.y; a0z += r0*wv.z; a0w += r0*wv.w;
      a1x += r1*wv.x; a1y += r1*wv.y; a1z += r1*wv.z; a1w += r1*wv.w;
    }
    a0x += __shfl_xor(a0x, 32); a0y += __shfl_xor(a0y, 32);
    a0z += __shfl_xor(a0z, 32); a0w += __shfl_xor(a0w, 32);
    a1x += __shfl_xor(a1x, 32); a1y += __shfl_xor(a1y, 32);
    a1z += __shfl_xor(a1z, 32); a1w += __shfl_xor(a1w, 32);
    if (lane < 32) {
      RB[rA][c4+0] = a0x + mob[c4+0]; RB[rA][c4+1] = a0y + mob[c4+1];
      RB[rA][c4+2] = a0z + mob[c4+2]; RB[rA][c4+3] = a0w + mob[c4+3];
      RB[rB][c4+0] = a1x + mob[c4+0]; RB[rB][c4+1] = a1y + mob[c4+1];
      RB[rB][c4+2] = a1z + mob[c4+2]; RB[rB][c4+3] = a1w + mob[c4+3];
    }
  }
  // stage B: RA = gelu(RB @ w1 + b1)  (128 -> 128)
  {
    const int kk = lane >> 5;
    const int c4 = (lane & 31) << 2;
    float a0x=0.f,a0y=0.f,a0z=0.f,a0w=0.f, a1x=0.f,a1y=0.f,a1z=0.f,a1w=0.f;
    #pragma unroll 8
    for (int i = 0; i < 64; i++) {
      const int k = kk + (i << 1);
      const float4 wv = *(const float4*)&w1[(size_t)k * 128 + c4];
      const float r0 = RB[rA][k], r1 = RB[rB][k];
      a0x += r0*wv.x; a0y += r0*wv.y; a0z += r0*wv.z; a0w += r0*wv.w;
      a1x += r1*wv.x; a1y += r1*wv.y; a1z += r1*wv.z; a1w += r1*wv.w;
    }
    a0x += __shfl_xor(a0x, 32); a0y += __shfl_xor(a0y, 32);
    a0z += __shfl_xor(a0z, 32); a0w += __shfl_xor(a0w, 32);
    a1x += __shfl_xor(a1x, 32); a1y += __shfl_xor(a1y, 32);
    a1z += __shfl_xor(a1z, 32); a1w += __shfl_xor(a1w, 32);
    if (lane < 32) {
      RA[rA][c4+0] = gelu_f(a0x + b1[c4+0]); RA[rA][c4+1] = gelu_f(a0y + b1[c4+1]);
      RA[rA][c4+2] = gelu_f(a0z + b1[c4+2]); RA[rA][c4+3] = gelu_f(a0w + b1[c4+3]);
      RA[rB][c4+0] = gelu_f(a1x + b1[c4+0]); RA[rB][c4+1] = gelu_f(a1y + b1[c4+1]);
      RA[rB][c4+2] = gelu_f(a1z + b1[c4+2]); RA[rB][c4+3] = gelu_f(a1w + b1[c4+3]);
    }
  }
  // stage C: RB[:, :64] = gelu(RA @ w2 + b2)  (128 -> 64)
  {
    const int kk = lane >> 4;              // k residue 0..3
    const int c4 = (lane & 15) << 2;       // output col quad (0..60)
    float a0x=0.f,a0y=0.f,a0z=0.f,a0w=0.f, a1x=0.f,a1y=0.f,a1z=0.f,a1w=0.f;
    #pragma unroll 8
    for (int i = 0; i < 32; i++) {
      const int k = kk + (i << 2);
      const float4 wv = *(const float4*)&w2[(size_t)k * 64 + c4];
      const float r0 = RA[rA][k], r1 = RA[rB][k];
      a0x += r0*wv.x; a0y += r0*wv.y; a0z += r0*wv.z; a0w += r0*wv.w;
      a1x += r1*wv.x; a1y += r1*wv.y; a1z += r1*wv.z; a1w += r1*wv.w;
    }
    a0x += __shfl_xor(a0x, 16); a0y += __shfl_xor(a0y, 16);
    a0z += __shfl_xor(a0z, 16); a0w += __shfl_xor(a0w, 16);
    a1x += __shfl_xor(a1x, 16); a1y += __shfl_xor(a1y, 16);
    a1z += __shfl_xor(a1z, 16); a1w += __shfl_xor(a1w, 16);
    a0x += __shfl_xor(a0x, 32); a0y += __shfl_xor(a0y, 32);
    a0z += __shfl_xor(a0z, 32); a0w += __shfl_xor(a0w, 32);
    a1x += __shfl_xor(a1x, 32); a1y += __shfl_xor(a1y, 32);
    a1z += __shfl_xor(a1z, 32); a1w += __shfl_xor(a1w, 32);
    if (lane < 16) {
      RB[rA][c4+0] = gelu_f(a0x + b2[c4+0]); RB[rA][c4+1] = gelu_f(a0y + b2[c4+1]);
      RB[rA][c4+2] = gelu_f(a0z + b2[c4+2]); RB[rA][c4+3] = gelu_f(a0w + b2[c4+3]);
      RB[rB][c4+0] = gelu_f(a1x + b2[c4+0]); RB[rB][c4+1] = gelu_f(a1y + b2[c4+1]);
      RB[rB][c4+2] = gelu_f(a1z + b2[c4+2]); RB[rB][c4+3] = gelu_f(a1w + b2[c4+3]);
    }
  }
  // stage D: out = RB[:, :64] @ w3 + b3   (64 -> 3)
  if (lane < 3) {
    #pragma unroll
    for (int rr = 0; rr < 2; rr++) {
      const int row = w * 2 + rr;
      float s = b3[lane];
      for (int c = 0; c < 64; c++) s += RB[row][c] * w3[c * 3 + lane];
      out[(size_t)(n0 + row) * 3 + lane] = s;
    }
  }
}

extern "C" void kernel_launch(void* const* d_in, const int* in_sizes, int n_in,
                              void* d_out, int out_size, void* d_ws, size_t ws_size,
                              hipStream_t stream) {
  const int*   x         = (const int*)d_in[0];
  const int*   eidx      = (const int*)d_in[1];
  const float* edge_attr = (const float*)d_in[2];
  const float* atom_emb  = (const float*)d_in[4];
  const float* edge_w    = (const float*)d_in[5];
  const float* edge_b    = (const float*)d_in[6];
  const float* wq        = (const float*)d_in[7];
  const float* bq        = (const float*)d_in[8];
  const float* wk        = (const float*)d_in[9];
  const float* bk        = (const float*)d_in[10];
  const float* wv        = (const float*)d_in[11];
  const float* bv        = (const float*)d_in[12];
  const float* we        = (const float*)d_in[13];
  const float* wskip     = (const float*)d_in[14];
  const float* bskip     = (const float*)d_in[15];
  const float* ln_g      = (const float*)d_in[16];
  const float* ln_b      = (const float*)d_in[17];
  const float* mha_in_w  = (const float*)d_in[18];
  const float* mha_in_b  = (const float*)d_in[19];
  const float* mha_out_w = (const float*)d_in[20];
  const float* mha_out_b = (const float*)d_in[21];
  const float* w1        = (const float*)d_in[22];
  const float* b1        = (const float*)d_in[23];
  const float* w2        = (const float*)d_in[24];
  const float* b2        = (const float*)d_in[25];
  const float* w3        = (const float*)d_in[26];
  const float* b3        = (const float*)d_in[27];

  float* ws   = (float*)d_ws;
  float* h    = ws;
  float* ef   = h + 524288;
  float* qb   = ef + 524288;
  float* kvb  = qb + 4194304;       // 8388608 floats: K/V interleaved [n][2048]
  float* qe   = kvb + 8388608;
  float* big  = qe + 1048576;       // 4194304 floats, subdivided:
  float* skb  = big + 1048576;      //   524288
  // split-bf16 buffers carved from the tail of big (5242880 shorts available):
  unsigned short* hhi  = (unsigned short*)(big + 1572864);   // 524288 shorts
  unsigned short* hlo  = hhi + 524288;                       // 524288 shorts
  unsigned short* wthi = hlo + 524288;                       // 1769472 shorts
  unsigned short* wtlo = wthi + 1769472;                     // 1769472 shorts (= 4587520 total, fits)
  float* sbuf = big + 4194304;      // 1048576 (scratch region)
  // MHA-phase aliases (layer-phase buffers dead by then)
  float* qkvm = qb;                 // N*384
  float* pm   = sbuf;               // 262144 (32768 rows x 8 splits)
  float* pz   = sbuf + 262144;      // 262144
  float* pacc = big;                // 4194304 (layer-phase big contents dead)
  int* counts = (int*)(sbuf + 1048576);
  int* offs   = counts + 4100;
  int* heads  = offs + 4100;        // (unused; kept for layout stability)
  int* elist  = heads + 4100;
  float* bqe  = (float*)(elist + 16384);   // 1024 floats

  k_init<<<2048, 256, 0, stream>>>(x, atom_emb, edge_attr, edge_w, edge_b, h, ef, counts,
                                   hhi, hlo);
  k_hist<<<64, 256, 0, stream>>>(eidx, counts);
  k_scan2<<<1, 1024, 0, stream>>>(counts, offs, eidx, elist);
  k_wcvt<<<dim3(16, 2, 16), 256, 0, stream>>>(wq, wk, wv, wskip, wthi, wtlo);
  k_wqe<<<32, 256, 0, stream>>>(wq, bq, we, wthi, wtlo, bqe);

  for (int i = 0; i < NLAYERS; i++) {
    const float* bq_i  = bq + (size_t)i * 1024;
    const float* bk_i  = bk + (size_t)i * 1024;
    const float* bv_i  = bv + (size_t)i * 1024;
    const float* we_i  = we + (size_t)i * 32768;
    const float* bsk_i = bskip + (size_t)i * 128;
    const float* g_i   = ln_g + (size_t)i * 128;
    const float* b_i   = ln_b + (size_t)i * 128;
    const unsigned short* wth_i = wthi + (size_t)i * WT_STRIDE;
    const unsigned short* wtl_i = wtlo + (size_t)i * WT_STRIDE;

    k_mfqkv<<<dim3(54, 64), 256, 0, stream>>>(hhi, hlo, wth_i, wtl_i,
                                              bq_i, bk_i, bv_i, bsk_i, bqe + i * 256,
                                              qb, kvb, skb, qe);
    k_edgepost<<<1024, 256, 0, stream>>>(qb, kvb, qe, ef, offs, elist, eidx,
                                         we_i, skb, g_i, b_i, h, hhi, hlo);
  }

  k_gemm2<<<dim3(6, 64), 256, 0, stream>>>(h, mha_in_w, mha_in_b, qkvm, 384, 0);
  k_attn2b<<<dim3(8, 2, 64), 256, 0, stream>>>(qkvm, pm, pz, pacc);
  k_tail<<<512, 256, 0, stream>>>(pm, pz, pacc,
                                  mha_out_w, mha_out_b, w1, b1, w2, b2, w3, b3,
                                  (float*)d_out);
}